// Round 1
// baseline (4815.381 us; speedup 1.0000x reference)
//
#include <hip/hip_runtime.h>
#include <hip/hip_bf16.h>
#include <math.h>

#define TT 12
#define NN 50000
#define EE 800000
#define CC 128
#define HH 128

// ---------------------------------------------------------------------------
// Per-timestep graph prep
// ---------------------------------------------------------------------------

__global__ void zero_counts(int* __restrict__ count, float* __restrict__ gslot, int n) {
    int i = blockIdx.x * 256 + threadIdx.x;
    if (i < n) count[i] = 0;
    if (blockIdx.x == 0 && threadIdx.x < HH) gslot[threadIdx.x] = 0.0f;
}

__global__ void count_edges(const int* __restrict__ dst, int* __restrict__ count, int ne) {
    int e = blockIdx.x * 256 + threadIdx.x;
    if (e < ne) atomicAdd(&count[dst[e]], 1);
}

// Exclusive scan of count[] into row_ptr[]; 1024 elements per block.
__global__ __launch_bounds__(256) void scan1(const int* __restrict__ count,
                                             int* __restrict__ rp,
                                             int* __restrict__ bsum, int n) {
    __shared__ int sh[256];
    int tid = threadIdx.x;
    int base = blockIdx.x * 1024 + tid * 4;
    int v0 = (base + 0 < n) ? count[base + 0] : 0;
    int v1 = (base + 1 < n) ? count[base + 1] : 0;
    int v2 = (base + 2 < n) ? count[base + 2] : 0;
    int v3 = (base + 3 < n) ? count[base + 3] : 0;
    int ts = v0 + v1 + v2 + v3;
    sh[tid] = ts;
    __syncthreads();
    for (int off = 1; off < 256; off <<= 1) {
        int v = (tid >= off) ? sh[tid - off] : 0;
        __syncthreads();
        sh[tid] += v;
        __syncthreads();
    }
    int excl = sh[tid] - ts;
    if (base + 0 < n) rp[base + 0] = excl;
    if (base + 1 < n) rp[base + 1] = excl + v0;
    if (base + 2 < n) rp[base + 2] = excl + v0 + v1;
    if (base + 3 < n) rp[base + 3] = excl + v0 + v1 + v2;
    if (tid == 255) bsum[blockIdx.x] = sh[255];
}

__global__ __launch_bounds__(256) void scan2(int* __restrict__ bsum, int* __restrict__ rp,
                                             int nb, int n, int etot) {
    __shared__ int sh[256];
    int tid = threadIdx.x;
    int v = (tid < nb) ? bsum[tid] : 0;
    sh[tid] = v;
    __syncthreads();
    for (int off = 1; off < 256; off <<= 1) {
        int x = (tid >= off) ? sh[tid - off] : 0;
        __syncthreads();
        sh[tid] += x;
        __syncthreads();
    }
    if (tid < nb) bsum[tid] = sh[tid] - v;  // exclusive
    if (tid == 0) rp[n] = etot;
}

__global__ void scan3(int* __restrict__ rp, int* __restrict__ work,
                      const int* __restrict__ bsum, const int* __restrict__ count,
                      float* __restrict__ dinv, int n) {
    int i = blockIdx.x * 256 + threadIdx.x;
    if (i < n) {
        int v = rp[i] + bsum[i >> 10];
        rp[i] = v;
        work[i] = v;
        dinv[i] = rsqrtf(1.0f + (float)count[i]);
    }
}

__global__ void fill_csr(const int* __restrict__ src, const int* __restrict__ dst,
                         int* __restrict__ work, int* __restrict__ csr_src, int ne) {
    int e = blockIdx.x * 256 + threadIdx.x;
    if (e < ne) {
        int d = dst[e];
        int pos = atomicAdd(&work[d], 1);
        csr_src[pos] = src[e];
    }
}

// ---------------------------------------------------------------------------
// GEMM: Y[row][c] = dinv[row] * sum_k X[row][k] * W[k][c]     (X: [n,128], W: [128,128])
// block = 512 threads, 64 rows/block, 8 threads per row, 16 cols/thread
// ---------------------------------------------------------------------------
__global__ __launch_bounds__(512) void gemm_scale(const float* __restrict__ X,
                                                  const float* __restrict__ W,
                                                  const float* __restrict__ dinv,
                                                  float* __restrict__ Y, int nrows) {
    __shared__ float Ws[128 * 128];
    int tid = threadIdx.x;
    for (int i = tid * 4; i < 128 * 128; i += 512 * 4) {
        *(float4*)&Ws[i] = *(const float4*)&W[i];
    }
    __syncthreads();

    int row = blockIdx.x * 64 + (tid >> 3);
    int t = tid & 7;
    if (row >= nrows) return;

    const float* xrow = X + (size_t)row * 128;
    float4 acc0 = make_float4(0.f, 0.f, 0.f, 0.f);
    float4 acc1 = make_float4(0.f, 0.f, 0.f, 0.f);
    float4 acc2 = make_float4(0.f, 0.f, 0.f, 0.f);
    float4 acc3 = make_float4(0.f, 0.f, 0.f, 0.f);

    for (int k0 = 0; k0 < 128; k0 += 4) {
        float4 xq = *(const float4*)(xrow + k0);
#pragma unroll
        for (int kk = 0; kk < 4; ++kk) {
            float xv = (kk == 0) ? xq.x : (kk == 1) ? xq.y : (kk == 2) ? xq.z : xq.w;
            const float* wrow = &Ws[(k0 + kk) * 128 + t * 4];
            float4 w0 = *(const float4*)(wrow + 0);
            float4 w1 = *(const float4*)(wrow + 32);
            float4 w2 = *(const float4*)(wrow + 64);
            float4 w3 = *(const float4*)(wrow + 96);
            acc0.x += xv * w0.x; acc0.y += xv * w0.y; acc0.z += xv * w0.z; acc0.w += xv * w0.w;
            acc1.x += xv * w1.x; acc1.y += xv * w1.y; acc1.z += xv * w1.z; acc1.w += xv * w1.w;
            acc2.x += xv * w2.x; acc2.y += xv * w2.y; acc2.z += xv * w2.z; acc2.w += xv * w2.w;
            acc3.x += xv * w3.x; acc3.y += xv * w3.y; acc3.z += xv * w3.z; acc3.w += xv * w3.w;
        }
    }
    float dv = dinv[row];
    float* yrow = Y + (size_t)row * 128;
    acc0.x *= dv; acc0.y *= dv; acc0.z *= dv; acc0.w *= dv;
    acc1.x *= dv; acc1.y *= dv; acc1.z *= dv; acc1.w *= dv;
    acc2.x *= dv; acc2.y *= dv; acc2.z *= dv; acc2.w *= dv;
    acc3.x *= dv; acc3.y *= dv; acc3.z *= dv; acc3.w *= dv;
    *(float4*)(yrow + t * 4 + 0)  = acc0;
    *(float4*)(yrow + t * 4 + 32) = acc1;
    *(float4*)(yrow + t * 4 + 64) = acc2;
    *(float4*)(yrow + t * 4 + 96) = acc3;
}

// ---------------------------------------------------------------------------
// Aggregation: out[d] = relu(dinv[d] * (Ys[d] + sum_{e in csr[d]} Ys[src]) + b)
// 1 wave per node, 4 nodes per wave, block = 256 (4 waves -> 16 nodes/block)
// ---------------------------------------------------------------------------
__global__ __launch_bounds__(256) void agg_relu(const float* __restrict__ Ys,
                                                const int* __restrict__ csr_src,
                                                const int* __restrict__ row_ptr,
                                                const float* __restrict__ dinv,
                                                const float* __restrict__ bias,
                                                float* __restrict__ Hout, int n) {
    int wave = threadIdx.x >> 6;
    int lane = threadIdx.x & 63;
    int c = lane * 2;
    float2 bv = *(const float2*)(bias + c);
    int d0 = blockIdx.x * 16 + wave * 4;
#pragma unroll
    for (int cnt = 0; cnt < 4; ++cnt) {
        int d = d0 + cnt;
        if (d >= n) break;
        float2 self = *(const float2*)(Ys + (size_t)d * 128 + c);
        float accx = self.x, accy = self.y;
        float acc2x = 0.f, acc2y = 0.f;
        int e = row_ptr[d];
        int e1 = row_ptr[d + 1];
        for (; e + 1 < e1; e += 2) {
            int s0 = csr_src[e];
            int s1 = csr_src[e + 1];
            float2 v0 = *(const float2*)(Ys + (size_t)s0 * 128 + c);
            float2 v1 = *(const float2*)(Ys + (size_t)s1 * 128 + c);
            accx += v0.x; accy += v0.y;
            acc2x += v1.x; acc2y += v1.y;
        }
        if (e < e1) {
            int s0 = csr_src[e];
            float2 v0 = *(const float2*)(Ys + (size_t)s0 * 128 + c);
            accx += v0.x; accy += v0.y;
        }
        accx += acc2x; accy += acc2y;
        float dv = dinv[d];
        float2 o;
        o.x = fmaxf(accx * dv + bv.x, 0.0f);
        o.y = fmaxf(accy * dv + bv.y, 0.0f);
        *(float2*)(Hout + (size_t)d * 128 + c) = o;
    }
}

// Same aggregation but output is mean-pool partial sums (relu'd rows summed over
// this block's nodes, atomically added into gout[128]).
__global__ __launch_bounds__(256) void agg_relu_pool(const float* __restrict__ Ys,
                                                     const int* __restrict__ csr_src,
                                                     const int* __restrict__ row_ptr,
                                                     const float* __restrict__ dinv,
                                                     const float* __restrict__ bias,
                                                     float* __restrict__ gout, int n) {
    __shared__ float pool[4][128];
    int wave = threadIdx.x >> 6;
    int lane = threadIdx.x & 63;
    int c = lane * 2;
    float2 bv = *(const float2*)(bias + c);
    float px = 0.f, py = 0.f;
    int d0 = blockIdx.x * 16 + wave * 4;
#pragma unroll
    for (int cnt = 0; cnt < 4; ++cnt) {
        int d = d0 + cnt;
        if (d >= n) break;
        float2 self = *(const float2*)(Ys + (size_t)d * 128 + c);
        float accx = self.x, accy = self.y;
        float acc2x = 0.f, acc2y = 0.f;
        int e = row_ptr[d];
        int e1 = row_ptr[d + 1];
        for (; e + 1 < e1; e += 2) {
            int s0 = csr_src[e];
            int s1 = csr_src[e + 1];
            float2 v0 = *(const float2*)(Ys + (size_t)s0 * 128 + c);
            float2 v1 = *(const float2*)(Ys + (size_t)s1 * 128 + c);
            accx += v0.x; accy += v0.y;
            acc2x += v1.x; acc2y += v1.y;
        }
        if (e < e1) {
            int s0 = csr_src[e];
            float2 v0 = *(const float2*)(Ys + (size_t)s0 * 128 + c);
            accx += v0.x; accy += v0.y;
        }
        accx += acc2x; accy += acc2y;
        float dv = dinv[d];
        px += fmaxf(accx * dv + bv.x, 0.0f);
        py += fmaxf(accy * dv + bv.y, 0.0f);
    }
    pool[wave][c] = px;
    pool[wave][c + 1] = py;
    __syncthreads();
    int tid = threadIdx.x;
    if (tid < 128) {
        float s = pool[0][tid] + pool[1][tid] + pool[2][tid] + pool[3][tid];
        atomicAdd(&gout[tid], s);
    }
}

// ---------------------------------------------------------------------------
// GRU over T=12 steps + head. Single block, 384 threads.
// ---------------------------------------------------------------------------
__global__ __launch_bounds__(384) void gru_head(const float* __restrict__ gseq,
                                                const float* __restrict__ W_ih,
                                                const float* __restrict__ W_hh,
                                                const float* __restrict__ b_ih,
                                                const float* __restrict__ b_hh,
                                                const float* __restrict__ W_head,
                                                const float* __restrict__ b_head,
                                                float* __restrict__ out) {
    __shared__ float xs[128], hs[128], gi[384], gh[384];
    int tid = threadIdx.x;
    if (tid < 128) hs[tid] = 0.0f;
    __syncthreads();
    const float inv_n = 1.0f / (float)NN;
    for (int t = 0; t < TT; ++t) {
        if (tid < 128) xs[tid] = gseq[t * 128 + tid] * inv_n;
        __syncthreads();
        float a = b_ih[tid];
        float b = b_hh[tid];
        const float* wi = W_ih + (size_t)tid * 128;
        const float* wh = W_hh + (size_t)tid * 128;
        for (int k = 0; k < 128; k += 4) {
            float4 wiv = *(const float4*)(wi + k);
            float4 whv = *(const float4*)(wh + k);
            float4 xv = *(const float4*)(xs + k);
            float4 hv = *(const float4*)(hs + k);
            a += wiv.x * xv.x + wiv.y * xv.y + wiv.z * xv.z + wiv.w * xv.w;
            b += whv.x * hv.x + whv.y * hv.y + whv.z * hv.z + whv.w * hv.w;
        }
        gi[tid] = a;
        gh[tid] = b;
        __syncthreads();
        if (tid < 128) {
            float r = 1.0f / (1.0f + expf(-(gi[tid] + gh[tid])));
            float z = 1.0f / (1.0f + expf(-(gi[128 + tid] + gh[128 + tid])));
            float nval = tanhf(gi[256 + tid] + r * gh[256 + tid]);
            hs[tid] = (1.0f - z) * nval + z * hs[tid];
        }
        __syncthreads();
    }
    if (tid < 128) {
        float a = b_head[tid];
        const float* w = W_head + (size_t)tid * 128;
        float s = 0.f;
        for (int k = 0; k < 128; k += 4) {
            float4 wv = *(const float4*)(w + k);
            s += wv.x * hs[k] + wv.y * hs[k + 1] + wv.z * hs[k + 2] + wv.w * hs[k + 3];
        }
        out[tid] = a + s;
    }
}

// ---------------------------------------------------------------------------

extern "C" void kernel_launch(void* const* d_in, const int* in_sizes, int n_in,
                              void* d_out, int out_size, void* d_ws, size_t ws_size,
                              hipStream_t stream) {
    const float* x_seq  = (const float*)d_in[0];
    const int*   ei_seq = (const int*)d_in[1];
    const float* W1     = (const float*)d_in[2];
    const float* b1     = (const float*)d_in[3];
    const float* W2     = (const float*)d_in[4];
    const float* b2     = (const float*)d_in[5];
    const float* W_ih   = (const float*)d_in[6];
    const float* W_hh   = (const float*)d_in[7];
    const float* b_ih   = (const float*)d_in[8];
    const float* b_hh   = (const float*)d_in[9];
    const float* W_head = (const float*)d_in[10];
    const float* b_head = (const float*)d_in[11];
    float* out = (float*)d_out;

    // workspace layout
    char* ws = (char*)d_ws;
    size_t off = 0;
    auto alloc = [&](size_t bytes) -> char* {
        char* p = ws + off;
        off += (bytes + 255) & ~(size_t)255;
        return p;
    };
    float* Ys      = (float*)alloc((size_t)NN * 128 * 4);
    float* Hbuf    = (float*)alloc((size_t)NN * 128 * 4);
    float* dinv    = (float*)alloc((size_t)NN * 4);
    int*   count   = (int*)alloc((size_t)NN * 4);
    int*   row_ptr = (int*)alloc((size_t)(NN + 1) * 4);
    int*   work    = (int*)alloc((size_t)NN * 4);
    int*   bsum    = (int*)alloc(256 * 4);
    int*   csr_src = (int*)alloc((size_t)EE * 4);
    float* gseq    = (float*)alloc((size_t)TT * 128 * 4);
    (void)ws_size; (void)n_in; (void)in_sizes; (void)out_size;

    const int gridN  = (NN + 255) / 256;        // 196
    const int gridE  = (EE + 255) / 256;        // 3125
    const int scanB  = (NN + 1023) / 1024;      // 49
    const int gemmB  = (NN + 63) / 64;          // 782
    const int aggB   = (NN + 15) / 16;          // 3125

    for (int t = 0; t < TT; ++t) {
        const int* src = ei_seq + (size_t)t * 2 * EE;
        const int* dst = src + EE;
        const float* Xt = x_seq + (size_t)t * NN * CC;

        zero_counts<<<gridN, 256, 0, stream>>>(count, gseq + t * 128, NN);
        count_edges<<<gridE, 256, 0, stream>>>(dst, count, EE);
        scan1<<<scanB, 256, 0, stream>>>(count, row_ptr, bsum, NN);
        scan2<<<1, 256, 0, stream>>>(bsum, row_ptr, scanB, NN, EE);
        scan3<<<gridN, 256, 0, stream>>>(row_ptr, work, bsum, count, dinv, NN);
        fill_csr<<<gridE, 256, 0, stream>>>(src, dst, work, csr_src, EE);

        gemm_scale<<<gemmB, 512, 0, stream>>>(Xt, W1, dinv, Ys, NN);
        agg_relu<<<aggB, 256, 0, stream>>>(Ys, csr_src, row_ptr, dinv, b1, Hbuf, NN);
        gemm_scale<<<gemmB, 512, 0, stream>>>(Hbuf, W2, dinv, Ys, NN);
        agg_relu_pool<<<aggB, 256, 0, stream>>>(Ys, csr_src, row_ptr, dinv, b2,
                                                gseq + t * 128, NN);
    }

    gru_head<<<1, 384, 0, stream>>>(gseq, W_ih, W_hh, b_ih, b_hh, W_head, b_head, out);
}